// Round 4
// baseline (532.936 us; speedup 1.0000x reference)
//
#include <hip/hip_runtime.h>
#include <hip/hip_bf16.h>

typedef __hip_bfloat16 bf16;
typedef __attribute__((ext_vector_type(8))) short short8;
typedef __attribute__((ext_vector_type(4))) short short4_t;
typedef __attribute__((ext_vector_type(4))) float float4_t;
typedef __attribute__((ext_vector_type(2))) float float2v;
typedef __attribute__((ext_vector_type(2))) unsigned int uint2v;

__device__ __forceinline__ short f2bs(float f) {
    bf16 b = __float2bfloat16(f);
    return *(short*)&b;
}

// ---------------------------------------------------------------- CSR build
__global__ __launch_bounds__(256) void zero_kernel(int* __restrict__ a, int n) {
    int i = blockIdx.x * 256 + threadIdx.x;
    if (i < n) a[i] = 0;
}

__global__ __launch_bounds__(256) void count_kernel(const int* __restrict__ ei,
                                                    int* __restrict__ cnt, int E, int N) {
    int e = blockIdx.x * 256 + threadIdx.x;
    if (e >= E + N) return;
    int d = (e < E) ? ei[(size_t)E + e] : (e - E);   // self-loop for e>=E
    atomicAdd(&cnt[d], 1);
}

__global__ __launch_bounds__(1024) void scan_kernel(const int* __restrict__ cnt,
                                                    int* __restrict__ rowptr, int N) {
    __shared__ int ps[1024];
    const int tid = threadIdx.x;
    const int chunk = (N + 1023) / 1024;
    const int base = tid * chunk;
    int s = 0;
    for (int i = 0; i < chunk; ++i) { int j = base + i; if (j < N) s += cnt[j]; }
    ps[tid] = s;
    __syncthreads();
    for (int off = 1; off < 1024; off <<= 1) {
        int v = (tid >= off) ? ps[tid - off] : 0;
        __syncthreads();
        ps[tid] += v;
        __syncthreads();
    }
    int run = (tid == 0) ? 0 : ps[tid - 1];
    for (int i = 0; i < chunk; ++i) {
        int j = base + i;
        if (j < N) { rowptr[j] = run; run += cnt[j]; }
    }
    if (tid == 1023) rowptr[N] = run;
}

// stores BYTE offsets (src * 4096): both gat layers use row stride 2048 bf16
__global__ __launch_bounds__(256) void scatter_kernel(const int* __restrict__ ei,
                                                      const int* __restrict__ rowptr,
                                                      int* __restrict__ cursor,
                                                      int* __restrict__ csr_off,
                                                      int E, int N) {
    int e = blockIdx.x * 256 + threadIdx.x;
    if (e >= E + N) return;
    int s, d;
    if (e < E) { s = ei[e]; d = ei[(size_t)E + e]; }
    else       { s = e - E; d = e - E; }
    int pos = atomicAdd(&cursor[d], 1);
    csr_off[rowptr[d] + pos] = s * 4096;
}

// ---------------------------------------------------------------- weight prep
__global__ __launch_bounds__(256) void transpose_w_kernel(
        const float* __restrict__ W_in,
        const float* __restrict__ c1_Wl, const float* __restrict__ c1_Wr,
        const float* __restrict__ a_Wl, const float* __restrict__ a_Wr,
        const float* __restrict__ k_Wl, const float* __restrict__ k_Wr,
        bf16* __restrict__ Wt) {
    __shared__ float tile[32][33];
    const float* src; int nc, drow;
    switch (blockIdx.z) {
        case 0: src = W_in;  nc = 128; drow = 0;    break;
        case 1: src = c1_Wl; nc = 512; drow = 128;  break;
        case 2: src = c1_Wr; nc = 512; drow = 640;  break;
        case 3: src = a_Wl;  nc = 512; drow = 1152; break;
        case 4: src = a_Wr;  nc = 512; drow = 1664; break;
        case 5: src = k_Wl;  nc = 512; drow = 2176; break;
        default: src = k_Wr; nc = 512; drow = 2688; break;
    }
    const int n0 = blockIdx.x * 32;
    if (n0 >= nc) return;
    const int k0 = blockIdx.y * 32;
    const int tx = threadIdx.x & 31, ty = threadIdx.x >> 5;
#pragma unroll
    for (int i = 0; i < 4; ++i)
        tile[ty + i * 8][tx] = src[(size_t)(k0 + ty + i * 8) * nc + n0 + tx];
    __syncthreads();
#pragma unroll
    for (int i = 0; i < 4; ++i)
        Wt[(size_t)(drow + n0 + ty + i * 8) * 128 + k0 + tx] =
            __float2bfloat16(tile[tx][ty + i * 8]);
}

__global__ __launch_bounds__(256) void bias_kernel(
        const float* __restrict__ c1_bl, const float* __restrict__ c1_br,
        const float* __restrict__ a_bl, const float* __restrict__ a_br,
        const float* __restrict__ k_bl, const float* __restrict__ k_br,
        float* __restrict__ b1, float* __restrict__ bak) {
    int i = blockIdx.x * 256 + threadIdx.x;
    if (i < 1024) {
        b1[i] = (i < 512) ? c1_bl[i] : c1_br[i - 512];
    } else if (i < 3072) {
        int j = i - 1024;
        const float* b = (j < 512) ? a_bl : (j < 1024) ? a_br : (j < 1536) ? k_bl : k_br;
        bak[j] = b[j & 511];
    }
}

// ---------------------------------------------------------------- MFMA GEMM
__global__ __launch_bounds__(256, 2) void gemm_mfma_kernel(
        const float* __restrict__ A, const bf16* __restrict__ Wt,
        const float* __restrict__ bias,
        float* __restrict__ outF, bf16* __restrict__ outB,
        int M, int ldc, int relu) {
    __shared__ short As[128][136];   // [m][k]
    __shared__ short Bs[128][136];   // [n][k]
    const int tid = threadIdx.x;
    const int m0 = blockIdx.x * 128;
    const int n0 = blockIdx.y * 128;

#pragma unroll
    for (int i = 0; i < 16; ++i) {            // stage A
        int idx = i * 256 + tid;
        int r = idx >> 5, k4 = (idx & 31) * 4;
        int gm = m0 + r;
        float4 v = (gm < M) ? *(const float4*)&A[(size_t)gm * 128 + k4]
                            : make_float4(0.f, 0.f, 0.f, 0.f);
        short4_t s;
        s.x = f2bs(v.x); s.y = f2bs(v.y); s.z = f2bs(v.z); s.w = f2bs(v.w);
        *(short4_t*)&As[r][k4] = s;
    }
#pragma unroll
    for (int i = 0; i < 8; ++i) {             // stage B
        int idx = i * 256 + tid;
        int nr = idx >> 4, k8 = (idx & 15) * 8;
        *(short8*)&Bs[nr][k8] = *(const short8*)&Wt[(size_t)(n0 + nr) * 128 + k8];
    }
    __syncthreads();

    const int lane = tid & 63;
    const int w = tid >> 6;
    const int wm = (w >> 1) * 64, wn = (w & 1) * 64;
    const int fr = lane & 15;
    const int fq = (lane >> 4) * 8;

    float4_t acc[4][4] = {};
#pragma unroll
    for (int kk = 0; kk < 128; kk += 32) {
        short8 a[4], b[4];
#pragma unroll
        for (int t = 0; t < 4; ++t) a[t] = *(const short8*)&As[wm + t * 16 + fr][kk + fq];
#pragma unroll
        for (int t = 0; t < 4; ++t) b[t] = *(const short8*)&Bs[wn + t * 16 + fr][kk + fq];
#pragma unroll
        for (int ti = 0; ti < 4; ++ti)
#pragma unroll
            for (int tj = 0; tj < 4; ++tj)
                acc[ti][tj] = __builtin_amdgcn_mfma_f32_16x16x32_bf16(
                    a[ti], b[tj], acc[ti][tj], 0, 0, 0);
    }

    const int r0 = (lane >> 4) * 4;           // C/D: col=lane&15, row=quad*4+reg
#pragma unroll
    for (int ti = 0; ti < 4; ++ti) {
#pragma unroll
        for (int tj = 0; tj < 4; ++tj) {
            int col = n0 + wn + tj * 16 + fr;
            float bz = bias[col];
#pragma unroll
            for (int r = 0; r < 4; ++r) {
                size_t row = m0 + wm + ti * 16 + r0 + r;
                float v = acc[ti][tj][r] + bz;
                if (relu) v = fmaxf(v, 0.f);
                if (outF) outF[row * ldc + col] = v;
                else      outB[row * ldc + col] = __float2bfloat16(v);
            }
        }
    }
}

// ---------------------------------------------------------------- fused GATv2 layer
// wave = node (4 nodes/block, no LDS, no barriers). 16-lane group = head; lane
// owns bytes lane*16 of the contiguous 1024B 4-head row slice -> ONE
// global_load_dwordx4 per edge. Depth-4 software-pipelined gather ring.
// No-max softmax (scores O(+-4), clamp 60; shift-invariant vs ref).
// blockIdx.y selects param set (fused actor/critic launch).
#define GAT_PF 4
__global__ __launch_bounds__(256) void gat_kernel(
        const bf16* __restrict__ xl0, const bf16* __restrict__ xr0,
        const float* __restrict__ att0, const float* __restrict__ res0,
        const float* __restrict__ gb0, const float* __restrict__ lng0,
        const float* __restrict__ lnb0, const float* __restrict__ hw0,
        const float* __restrict__ hb0, float* __restrict__ out0,
        const bf16* __restrict__ xl1, const bf16* __restrict__ xr1,
        const float* __restrict__ att1, const float* __restrict__ res1,
        const float* __restrict__ gb1, const float* __restrict__ lng1,
        const float* __restrict__ lnb1, const float* __restrict__ hw1,
        const float* __restrict__ hb1, float* __restrict__ out1,
        const int* __restrict__ rowptr, const int* __restrict__ csr_off,
        int N, int mode) {
    const int node = blockIdx.x * 4 + (threadIdx.x >> 6);
    if (node >= N) return;
    const bool yb = blockIdx.y != 0;
    const bf16*  xl  = yb ? xl1  : xl0;
    const bf16*  xr  = yb ? xr1  : xr0;
    const float* att = yb ? att1 : att0;
    const float* res = yb ? res1 : res0;
    const float* gb  = yb ? gb1  : gb0;
    const float* lng = yb ? lng1 : lng0;
    const float* lnb = yb ? lnb1 : lnb0;
    const float* hw  = yb ? hw1  : hw0;
    const float* hb  = yb ? hb1  : hb0;
    float*       out = yb ? out1 : out0;

    const int lane = threadIdx.x & 63;
    const int sl = lane & 15;            // 16 lanes per head-group
    const int cb = sl * 8;               // 8 channels per lane

    float2v c1[4], c2[4], xr2[4];
    {
        const float* ap = att + (lane << 3);            // head*128 + sl*8
        short8 v = *(const short8*)((const char*)xr + (size_t)node * 4096 + lane * 16);
        const unsigned int* uv = (const unsigned int*)&v;
#pragma unroll
        for (int j = 0; j < 4; ++j) {
            float a0 = ap[2 * j], a1 = ap[2 * j + 1];
            c1[j].x = 0.6f * a0; c1[j].y = 0.6f * a1;
            c2[j].x = 0.4f * a0; c2[j].y = 0.4f * a1;
            unsigned u = uv[j];
            xr2[j].x = __uint_as_float(u << 16);
            xr2[j].y = __uint_as_float(u & 0xffff0000u);
        }
    }
    const int rs = rowptr[node], re = rowptr[node + 1];
    const int cnt = re - rs;                            // >=1 (self-loop)
    const char* xbase = (const char*)xl + lane * 16;
    const int* co = csr_off + rs;

    short8 buf[GAT_PF];
#pragma unroll
    for (int d = 0; d < GAT_PF; ++d) {                  // prologue: fill the ring
        int idx = (d < cnt) ? d : 0;
        buf[d] = *(const short8*)(xbase + co[idx]);
    }

    float l = 0.f;
    float2v acc2[4] = {};
    for (int base = 0; base < cnt; base += GAT_PF) {
#pragma unroll
        for (int d = 0; d < GAT_PF; ++d) {
            const int idx = base + d;
            short8 cur = buf[d];
            const int nidx = idx + GAT_PF;
            if (nidx < cnt)                              // wave-uniform refill
                buf[d] = *(const short8*)(xbase + co[nidx]);
            const unsigned int* uv = (const unsigned int*)&cur;
            float2v p2 = {0.f, 0.f};
            float2v xs[4];
#pragma unroll
            for (int j = 0; j < 4; ++j) {
                unsigned u = uv[j];
                float2v x;
                x.x = __uint_as_float(u << 16);
                x.y = __uint_as_float(u & 0xffff0000u);
                xs[j] = x;
                float2v t = x + xr2[j];
                float2v ta = __builtin_bit_cast(float2v,
                               __builtin_bit_cast(uint2v, t) & 0x7fffffffu);
                p2 = __builtin_elementwise_fma(c1[j], t, p2);
                p2 = __builtin_elementwise_fma(c2[j], ta, p2);
            }
            float p = p2.x + p2.y;
            p += __shfl_xor(p, 1, 64);                   // per-head 16-lane reduce
            p += __shfl_xor(p, 2, 64);
            p += __shfl_xor(p, 4, 64);
            p += __shfl_xor(p, 8, 64);
            float wv = (idx < cnt) ? __expf(fminf(p, 60.f)) : 0.f;
            l += wv;
            float2v ws = {wv, wv};
#pragma unroll
            for (int j = 0; j < 4; ++j)
                acc2[j] = __builtin_elementwise_fma(ws, xs[j], acc2[j]);
        }
    }

    // per-head alpha-normalize + 1/4 head-mean, then sum heads (groups)
    const float inv = 0.25f / (l + 1e-16f);
    float* af = (float*)acc2;
#pragma unroll
    for (int j = 0; j < 8; ++j) af[j] *= inv;
#pragma unroll
    for (int j = 0; j < 8; ++j) {
        af[j] += __shfl_xor(af[j], 16, 64);
        af[j] += __shfl_xor(af[j], 32, 64);
    }

    // epilogue: + bias + residual, LayerNorm, ReLU (all lanes redundant x4)
    float v[8];
    {
        const float* rp = res + (size_t)node * 128 + cb;
        const float* gp = gb + cb;
#pragma unroll
        for (int j = 0; j < 8; ++j) v[j] = af[j] + gp[j] + rp[j];
    }
    float s1 = 0.f, s2 = 0.f;
#pragma unroll
    for (int j = 0; j < 8; ++j) { s1 += v[j]; s2 += v[j] * v[j]; }
    s1 += __shfl_xor(s1, 1, 64); s2 += __shfl_xor(s2, 1, 64);
    s1 += __shfl_xor(s1, 2, 64); s2 += __shfl_xor(s2, 2, 64);
    s1 += __shfl_xor(s1, 4, 64); s2 += __shfl_xor(s2, 4, 64);
    s1 += __shfl_xor(s1, 8, 64); s2 += __shfl_xor(s2, 8, 64);
    const float mu = s1 * 0.0078125f;
    const float var = s2 * 0.0078125f - mu * mu;
    const float rstd = rsqrtf(var + 1e-5f);
    float y[8];
    {
        const float* gp = lng + cb;
        const float* bp = lnb + cb;
#pragma unroll
        for (int j = 0; j < 8; ++j)
            y[j] = fmaxf(fmaf((v[j] - mu) * rstd, gp[j], bp[j]), 0.f);
    }
    if (mode == 0) {
        if (lane < 16) {                                 // group 0 writes 32B/lane
            float* op = (float*)out + (size_t)node * 128 + cb;
            *(float4*)op = make_float4(y[0], y[1], y[2], y[3]);
            *(float4*)(op + 4) = make_float4(y[4], y[5], y[6], y[7]);
        }
    } else {
        const float* wp = hw + cb;
        float d = 0.f;
#pragma unroll
        for (int j = 0; j < 8; ++j) d = fmaf(y[j], wp[j], d);
        d += __shfl_xor(d, 1, 64);
        d += __shfl_xor(d, 2, 64);
        d += __shfl_xor(d, 4, 64);
        d += __shfl_xor(d, 8, 64);
        if (lane == 0) out[node] = d + hb[0];
    }
}

// ---------------------------------------------------------------- launch
extern "C" void kernel_launch(void* const* d_in, const int* in_sizes, int n_in,
                              void* d_out, int out_size, void* d_ws, size_t ws_size,
                              hipStream_t stream) {
    const float* x      = (const float*)d_in[0];
    const int*   ei     = (const int*)  d_in[1];
    const float* W_in   = (const float*)d_in[2];
    const float* b_in   = (const float*)d_in[3];
    const float* c1_Wl  = (const float*)d_in[4];
    const float* c1_bl  = (const float*)d_in[5];
    const float* c1_Wr  = (const float*)d_in[6];
    const float* c1_br  = (const float*)d_in[7];
    const float* c1_att = (const float*)d_in[8];
    const float* c1_b   = (const float*)d_in[9];
    const float* ln1_g  = (const float*)d_in[10];
    const float* ln1_b  = (const float*)d_in[11];
    const float* a_Wl   = (const float*)d_in[12];
    const float* a_bl   = (const float*)d_in[13];
    const float* a_Wr   = (const float*)d_in[14];
    const float* a_br   = (const float*)d_in[15];
    const float* a_att  = (const float*)d_in[16];
    const float* a_b    = (const float*)d_in[17];
    const float* aln_g  = (const float*)d_in[18];
    const float* aln_b  = (const float*)d_in[19];
    const float* ah_W   = (const float*)d_in[20];
    const float* ah_b   = (const float*)d_in[21];
    const float* k_Wl   = (const float*)d_in[22];
    const float* k_bl   = (const float*)d_in[23];
    const float* k_Wr   = (const float*)d_in[24];
    const float* k_br   = (const float*)d_in[25];
    const float* k_att  = (const float*)d_in[26];
    const float* k_b    = (const float*)d_in[27];
    const float* kln_g  = (const float*)d_in[28];
    const float* kln_b  = (const float*)d_in[29];
    const float* kh_W   = (const float*)d_in[30];
    const float* kh_b   = (const float*)d_in[31];

    const int N  = in_sizes[0] / 128;       // 20000
    const int E  = in_sizes[1] / 2;         // 320000
    const int ET = E + N;
    const int MB = (N + 127) / 128;         // 157
    const int Npad = MB * 128;              // 20096

    char* ws = (char*)d_ws;
    size_t off = 0;
    auto alloc = [&](size_t bytes) -> void* {
        void* p = ws + off;
        off += (bytes + 255) & ~(size_t)255;
        return p;
    };
    int*   rowptr  = (int*)alloc((size_t)(N + 1) * 4);
    int*   cntcur  = (int*)alloc((size_t)2 * N * 4);   // cnt | cursor
    int*   csr_off = (int*)alloc((size_t)ET * 4);
    float* h0      = (float*)alloc((size_t)Npad * 128 * 4);
    float* h1      = (float*)alloc((size_t)Npad * 128 * 4);
    bf16*  Wt      = (bf16*)alloc((size_t)3200 * 128 * 2);
    float* b1cat   = (float*)alloc(1024 * 4);
    float* bakcat  = (float*)alloc(2048 * 4);
    bf16*  cat     = (bf16*)alloc((size_t)Npad * 2048 * 2);  // row stride 2048 always

    int* cnt    = cntcur;
    int* cursor = cntcur + N;
    const bf16* Wt_in = Wt;
    const bf16* Wt_1  = Wt + 128 * 128;
    const bf16* Wt_ak = Wt + 128 * 128 + 1024 * 128;

    float* out_logits = (float*)d_out;
    float* out_value  = (float*)d_out + N;

    // CSR (graph shared by all 3 GAT layers) + weight prep
    zero_kernel<<<(2 * N + 255) / 256, 256, 0, stream>>>(cntcur, 2 * N);
    count_kernel<<<(ET + 255) / 256, 256, 0, stream>>>(ei, cnt, E, N);
    transpose_w_kernel<<<dim3(16, 4, 7), 256, 0, stream>>>(
        W_in, c1_Wl, c1_Wr, a_Wl, a_Wr, k_Wl, k_Wr, Wt);
    bias_kernel<<<12, 256, 0, stream>>>(c1_bl, c1_br, a_bl, a_br, k_bl, k_br, b1cat, bakcat);
    scan_kernel<<<1, 1024, 0, stream>>>(cnt, rowptr, N);
    scatter_kernel<<<(ET + 255) / 256, 256, 0, stream>>>(ei, rowptr, cursor, csr_off, E, N);

    // h0 = relu(x @ W_in + b_in)
    gemm_mfma_kernel<<<dim3(MB, 1), 256, 0, stream>>>(x, Wt_in, b_in, h0, nullptr, N, 128, 1);
    // layer-1: [xl1|xr1] = h0 @ [Wl|Wr]  (bf16, cols 0..1023, row stride 2048)
    gemm_mfma_kernel<<<dim3(MB, 8), 256, 0, stream>>>(h0, Wt_1, b1cat, nullptr, cat, Npad, 2048, 0);
    gat_kernel<<<dim3((N + 3) / 4, 1), 256, 0, stream>>>(
        cat, cat + 512, c1_att, h0, c1_b, ln1_g, ln1_b, nullptr, nullptr, h1,
        cat, cat + 512, c1_att, h0, c1_b, ln1_g, ln1_b, nullptr, nullptr, h1,
        rowptr, csr_off, N, 0);
    // actor+critic: [xla|xra|xlk|xrk] = h1 @ [aWl|aWr|kWl|kWr]
    gemm_mfma_kernel<<<dim3(MB, 16), 256, 0, stream>>>(h1, Wt_ak, bakcat, nullptr, cat, Npad, 2048, 0);
    // fused actor (y=0) + critic (y=1) heads
    gat_kernel<<<dim3((N + 3) / 4, 2), 256, 0, stream>>>(
        cat, cat + 512, a_att, h1, a_b, aln_g, aln_b, ah_W, ah_b, out_logits,
        cat + 1024, cat + 1536, k_att, h1, k_b, kln_g, kln_b, kh_W, kh_b, out_value,
        rowptr, csr_off, N, 1);
}